// Round 15
// baseline (193.132 us; speedup 1.0000x reference)
//
#include <hip/hip_runtime.h>
#include <hip/hip_bf16.h>
#include <cstdint>

// Problem constants (fixed by reference)
#define NN 8192
#define HH 256
#define II 128
#define KORD 4
#define EE 262144
#define KW 1536          // GEMM K = 4*(256+128)
#define MW 1024          // GEMM output cols = 4 gates * 256
#define RCAP 128         // fixed row capacity (Poisson(32): P(>128) ~ 1e-40)
#define BK 64            // GEMM K-step (full 128B L2 lines per row)

typedef __attribute__((ext_vector_type(8))) short bf16x8;
typedef __attribute__((ext_vector_type(8))) unsigned short u16x8;
typedef __attribute__((ext_vector_type(4))) float f32x4;

__device__ __forceinline__ float bf2f(unsigned short u) {
    union { uint32_t i; float f; } x; x.i = ((uint32_t)u) << 16; return x.f;
}
__device__ __forceinline__ unsigned short f2bf(float f) {
    __hip_bfloat16 b = __float2bfloat16(f);
    return *(unsigned short*)&b;
}

// ---------------- pos layout handling (int32 vs int64 words) ----------------
__device__ __forceinline__ void read_pos(const int* __restrict__ pos, int flag,
                                         int e, int& r, int& c) {
    if (flag) { r = pos[4 * e]; c = pos[4 * e + 2]; }   // int64 little-endian
    else      { r = pos[2 * e]; c = pos[2 * e + 1]; }   // int32
}

// ---------------- tiny init: zero row counters + layout detect -------------
__global__ void init_small(uint32_t* __restrict__ rcnt,
                           const int* __restrict__ pos, int* __restrict__ flag) {
    int i = blockIdx.x * blockDim.x + threadIdx.x;
    if (i < NN) rcnt[i] = 0u;
    if (i == 0) {
        int f = 1;
        for (int k = 0; k < 128; ++k) {
            if (pos[2 * k + 1] != 0) { f = 0; break; }
        }
        *flag = f;
    }
}

// ---------------- scatter into fixed-stride rows ---------------------------
// meta = (e+1)<<13 | c  (c: 13 bits, e+1: 19 bits) ; value kept raw f32
__global__ void scatter_fixed(const int* __restrict__ pos, const int* __restrict__ flagp,
                              const float* __restrict__ lap,
                              uint32_t* __restrict__ rcnt, uint2* __restrict__ cpack) {
    int e = blockIdx.x * blockDim.x + threadIdx.x;
    if (e >= EE) return;
    int flag = *flagp;
    int r, c; read_pos(pos, flag, e, r, c);
    uint32_t slot = atomicAdd(&rcnt[r], 1u);
    if (slot < RCAP) {
        uint2 p;
        p.x = ((uint32_t)(e + 1) << 13) | (uint32_t)c;
        p.y = __float_as_uint(lap[e]);
        cpack[(size_t)r * RCAP + slot] = p;
    }
}

// ---------------- in-row dedup -> packed u32 (bf16val<<16 | col) -----------
__global__ __launch_bounds__(256) void dedup_rows(uint32_t* __restrict__ rcnt,
                                                  const uint2* __restrict__ cpack,
                                                  uint32_t* __restrict__ cpk) {
    int r = blockIdx.x * 4 + (threadIdx.x >> 6);
    int lane = threadIdx.x & 63;
    uint32_t lenu = rcnt[r];
    int len = (lenu > RCAP) ? RCAP : (int)lenu;
    const uint2* base = &cpack[(size_t)r * RCAP];
    uint32_t m0 = 0u, m1 = 0u;
    float v0 = 0.0f, v1 = 0.0f;
    if (lane < len) { uint2 p = base[lane]; m0 = p.x; v0 = __uint_as_float(p.y); }
    if (64 + lane < len) { uint2 p = base[64 + lane]; m1 = p.x; v1 = __uint_as_float(p.y); }
    bool lose0 = false, lose1 = false;
    int nchunk = (len + 63) >> 6;
    for (int ch = 0; ch < nchunk; ++ch) {
        int cl = len - ch * 64; if (cl > 64) cl = 64;
        for (int i = 0; i < cl; ++i) {
            uint32_t mi = __shfl(ch == 0 ? m0 : m1, i);
            lose0 |= (((mi ^ m0) & 8191u) == 0u) && (mi > m0);
            lose1 |= (((mi ^ m1) & 8191u) == 0u) && (mi > m1);
        }
    }
    uint32_t* ob = &cpk[(size_t)r * RCAP];
    if (lane < len)
        ob[lane] = ((uint32_t)f2bf(lose0 ? 0.0f : v0) << 16) | (m0 & 8191u);
    if (64 + lane < len)
        ob[64 + lane] = ((uint32_t)f2bf(lose1 ? 0.0f : v1) << 16) | (m1 & 8191u);
    if (lane == 0 && lenu > RCAP) rcnt[r] = RCAP;
}

// ---------------- SpMV on Amat columns, XCD-feature-sliced ------------------
// Slice s (=bid&7) handles a 64B (h) / 32B (x) column band for ALL rows.
// The same slice is written & re-gathered by the same XCD across levels ->
// gathers hit the local L2 instead of round-tripping L3/fabric.
__device__ __forceinline__ void spmv_seg(
    const uint32_t* __restrict__ rcnt, const uint32_t* __restrict__ cpk,
    unsigned short* Am, int cbsrc, int cbprev, int cbdst,
    float a, float b, int r, int lane) {
    uint32_t len = rcnt[r]; if (len > RCAP) len = RCAP;
    uint32_t s = (uint32_t)r * RCAP, e = s + len;
    int off = lane * 8;
    float acc[8];
#pragma unroll
    for (int j = 0; j < 8; ++j) acc[j] = 0.0f;
    uint32_t i = s;
    for (; i + 4 <= e; i += 4) {
        uint32_t p0 = cpk[i], p1 = cpk[i + 1], p2 = cpk[i + 2], p3 = cpk[i + 3];
        u16x8 g0 = *(const u16x8*)&Am[(size_t)(p0 & 8191u) * KW + cbsrc + off];
        u16x8 g1 = *(const u16x8*)&Am[(size_t)(p1 & 8191u) * KW + cbsrc + off];
        u16x8 g2 = *(const u16x8*)&Am[(size_t)(p2 & 8191u) * KW + cbsrc + off];
        u16x8 g3 = *(const u16x8*)&Am[(size_t)(p3 & 8191u) * KW + cbsrc + off];
        float v0 = bf2f((unsigned short)(p0 >> 16));
        float v1 = bf2f((unsigned short)(p1 >> 16));
        float v2 = bf2f((unsigned short)(p2 >> 16));
        float v3 = bf2f((unsigned short)(p3 >> 16));
#pragma unroll
        for (int j = 0; j < 8; ++j)
            acc[j] += v0 * bf2f(g0[j]) + v1 * bf2f(g1[j]) +
                      v2 * bf2f(g2[j]) + v3 * bf2f(g3[j]);
    }
    for (; i < e; ++i) {
        uint32_t p0 = cpk[i];
        u16x8 g0 = *(const u16x8*)&Am[(size_t)(p0 & 8191u) * KW + cbsrc + off];
        float v0 = bf2f((unsigned short)(p0 >> 16));
#pragma unroll
        for (int j = 0; j < 8; ++j) acc[j] += v0 * bf2f(g0[j]);
    }
    u16x8 ob;
    if (b != 0.0f) {
        u16x8 pv = *(const u16x8*)&Am[(size_t)r * KW + cbprev + off];
#pragma unroll
        for (int j = 0; j < 8; ++j) ob[j] = f2bf(a * acc[j] + b * bf2f(pv[j]));
    } else {
#pragma unroll
        for (int j = 0; j < 8; ++j) ob[j] = f2bf(a * acc[j]);
    }
    *(u16x8*)&Am[(size_t)r * KW + cbdst + off] = ob;
}

// grid: 1024 h-blocks (slice=bid&7, 64 rows x 4 lanes) +
//        512 x-blocks (slice=bid&7, 128 rows x 2 lanes)
__global__ __launch_bounds__(256) void spmv_cheb_dual(
    const uint32_t* __restrict__ rcnt, const uint32_t* __restrict__ cpk,
    unsigned short* Am,
    int sh, int ph, int dh,       // h col bases: src, prev, dst
    int sx, int px, int dx,       // x col bases
    float a, float b) {
    int bid = blockIdx.x, t = threadIdx.x;
    if (bid < 1024) {
        int s = (bid & 7) * 32;
        int r = (bid >> 3) * 64 + (t >> 2);
        int lane = t & 3;
        spmv_seg(rcnt, cpk, Am, sh + s, ph + s, dh + s, a, b, r, lane);
    } else {
        int b2 = bid - 1024;
        int s = (b2 & 7) * 16;
        int r = (b2 >> 3) * 128 + (t >> 1);
        int lane = t & 1;
        spmv_seg(rcnt, cpk, Am, sx + s, px + s, dx + s, a, b, r, lane);
    }
}

// ---------------- level-0 pack, slice-partitioned (same bid&7 mapping) -----
// 98304 4-elem units per slice (h: 8/row, x: 4/row); 384 blocks/slice.
__global__ void pack_T0(const float* __restrict__ h, const float* __restrict__ x,
                        unsigned short* __restrict__ Am) {
    int bid = blockIdx.x;
    int s = bid & 7;
    int u = (bid >> 3) * 256 + threadIdx.x;   // 0..98303
    int n, col;
    const float* src;
    if (u < 65536) {           // h: 8192 rows x 8 units of 4 cols
        n = u >> 3;
        col = s * 32 + (u & 7) * 4;
        src = &h[(size_t)n * HH + col];
    } else {                   // x: 8192 rows x 4 units of 4 cols
        int u2 = u - 65536;
        n = u2 >> 2;
        int cx = s * 16 + (u2 & 3) * 4;
        src = &x[(size_t)n * II + cx];
        col = 1024 + cx;
    }
    float4 v = *(const float4*)src;
    ushort4 pk;
    pk.x = f2bf(v.x); pk.y = f2bf(v.y); pk.z = f2bf(v.z); pk.w = f2bf(v.w);
    *(ushort4*)&Am[(size_t)n * KW + col] = pk;
}

// B matrix [1024][1536]: row m = g*256+h (gate-major, proven layout)
__global__ void pack_B(const float* __restrict__ Wfh, const float* __restrict__ Wih,
                       const float* __restrict__ Woh, const float* __restrict__ Wch,
                       const float* __restrict__ Wfx, const float* __restrict__ Wix,
                       const float* __restrict__ Wox, const float* __restrict__ Wcx,
                       __hip_bfloat16* __restrict__ Bm) {
    int idx = blockIdx.x * blockDim.x + threadIdx.x;  // over MW*KW
    if (idx >= MW * KW) return;
    int m = idx / KW, j = idx - m * KW;
    int g = m >> 8, hh = m & 255;
    const float* Wh = (g == 0) ? Wfh : (g == 1) ? Wih : (g == 2) ? Woh : Wch;
    const float* Wx = (g == 0) ? Wfx : (g == 1) ? Wix : (g == 2) ? Wox : Wcx;
    float v;
    if (j < 1024) { int k = j >> 8, f = j & 255; v = Wh[((size_t)k * HH + hh) * HH + f]; }
    else { int jj = j - 1024; int k = jj >> 7, f = jj & 127; v = Wx[((size_t)k * HH + hh) * II + f]; }
    Bm[idx] = __float2bfloat16(v);
}

// ---------------- bf16 MFMA GEMM: BK=64, dbuf 2-phase, slot-8 LDS swizzle ---
__device__ __forceinline__ void gload_lds16(const void* g, void* l) {
    __builtin_amdgcn_global_load_lds(
        (const __attribute__((address_space(1))) void*)g,
        (__attribute__((address_space(3))) void*)l, 16, 0, 0);
}

__device__ __forceinline__ void stage_side(const __hip_bfloat16* __restrict__ G,
                                           int r0, int kk, int t, short* lds) {
#pragma unroll
    for (int s = 0; s < 4; ++s) {
        int e = (s * 256 + t) * 8;        // elem in [128][64] tile
        int row = e >> 6;
        int kks = ((((e >> 3) & 7) ^ (row & 7)) << 3);  // pre-swizzled source
        gload_lds16(&G[(size_t)(r0 + row) * KW + kk + kks], &lds[e]);
    }
}

__global__ __launch_bounds__(256) void gemm_mfma(
    const __hip_bfloat16* __restrict__ A,   // [NN][KW]
    const __hip_bfloat16* __restrict__ B,   // [MW][KW]
    float* __restrict__ C) {                // [NN][MW]
    __shared__ short Alds[2][128 * BK];
    __shared__ short Blds[2][128 * BK];
    int bid = blockIdx.x;
    int sw = (bid & 7) * 64 + (bid >> 3);
    int m0 = (sw & 7) * 128;    // col tile
    int n0 = (sw >> 3) * 128;   // row tile
    int t = threadIdx.x;
    int w = t >> 6, l = t & 63;
    int wr = w >> 1, wc = w & 1;
    int lrow = l & 15, q = l >> 4;

    f32x4 acc[4][4];
#pragma unroll
    for (int i = 0; i < 4; ++i)
#pragma unroll
        for (int j = 0; j < 4; ++j) acc[i][j] = (f32x4)0.0f;

    stage_side(A, n0, 0, t, Alds[0]);
    stage_side(B, m0, 0, t, Blds[0]);
    __syncthreads();

    int cur = 0;
    for (int k0 = 0; k0 < KW; k0 += BK) {
        if (k0 + BK < KW) {
            stage_side(A, n0, k0 + BK, t, Alds[cur ^ 1]);
            stage_side(B, m0, k0 + BK, t, Blds[cur ^ 1]);
        }
#pragma unroll
        for (int h = 0; h < 2; ++h) {
            int sl = (((h << 2) | q) ^ (lrow & 7)) << 3;  // swizzled ds_read slot
            bf16x8 af[4], bfr[4];
#pragma unroll
            for (int i = 0; i < 4; ++i)
                af[i] = *(const bf16x8*)&Alds[cur][(wr * 64 + i * 16 + lrow) * BK + sl];
#pragma unroll
            for (int j = 0; j < 4; ++j)
                bfr[j] = *(const bf16x8*)&Blds[cur][(wc * 64 + j * 16 + lrow) * BK + sl];
#pragma unroll
            for (int i = 0; i < 4; ++i)
#pragma unroll
                for (int j = 0; j < 4; ++j)
                    acc[i][j] = __builtin_amdgcn_mfma_f32_16x16x32_bf16(af[i], bfr[j], acc[i][j], 0, 0, 0);
        }
        __syncthreads();
        cur ^= 1;
    }

    int r4 = (l >> 4) * 4;
#pragma unroll
    for (int i = 0; i < 4; ++i)
#pragma unroll
        for (int j = 0; j < 4; ++j)
#pragma unroll
            for (int r = 0; r < 4; ++r) {
                int row = n0 + wr * 64 + i * 16 + r4 + r;
                int col = m0 + wc * 64 + j * 16 + lrow;
                C[(size_t)row * MW + col] = acc[i][j][r];
            }
}

// ---------------- LSTM elementwise epilogue ----------------
__device__ __forceinline__ float sigmoidf_(float x) { return 1.0f / (1.0f + expf(-x)); }

__global__ __launch_bounds__(256) void lstm_ew(
    const float* __restrict__ C,            // [NN][MW] preacts, gate g at col g*256+h
    const float* __restrict__ bf, const float* __restrict__ bi,
    const float* __restrict__ bo, const float* __restrict__ bc,
    const float* __restrict__ cin, float* __restrict__ out) {
    int i = blockIdx.x * blockDim.x + threadIdx.x;  // over NN*HH/4
    if (i >= NN * HH / 4) return;
    int n = i >> 6;           // HH/4 = 64 float4 per row
    int h4 = (i & 63) * 4;
    size_t cb = (size_t)n * MW;
    size_t hb = (size_t)n * HH + h4;
    float4 pf = *(const float4*)&C[cb + 0 * HH + h4];
    float4 pi = *(const float4*)&C[cb + 1 * HH + h4];
    float4 po = *(const float4*)&C[cb + 2 * HH + h4];
    float4 pc = *(const float4*)&C[cb + 3 * HH + h4];
    float4 vbf = *(const float4*)&bf[hb];
    float4 vbi = *(const float4*)&bi[hb];
    float4 vbo = *(const float4*)&bo[hb];
    float4 vbc = *(const float4*)&bc[hb];
    float4 vc  = *(const float4*)&cin[hb];
    float4 hn, cn;
    {
        float fg = sigmoidf_(pf.x + vbf.x), ig = sigmoidf_(pi.x + vbi.x);
        float og = sigmoidf_(po.x + vbo.x), cg = tanhf(pc.x + vbc.x);
        cn.x = ig * cg + fg * vc.x; hn.x = og * tanhf(cn.x);
    }
    {
        float fg = sigmoidf_(pf.y + vbf.y), ig = sigmoidf_(pi.y + vbi.y);
        float og = sigmoidf_(po.y + vbo.y), cg = tanhf(pc.y + vbc.y);
        cn.y = ig * cg + fg * vc.y; hn.y = og * tanhf(cn.y);
    }
    {
        float fg = sigmoidf_(pf.z + vbf.z), ig = sigmoidf_(pi.z + vbi.z);
        float og = sigmoidf_(po.z + vbo.z), cg = tanhf(pc.z + vbc.z);
        cn.z = ig * cg + fg * vc.z; hn.z = og * tanhf(cn.z);
    }
    {
        float fg = sigmoidf_(pf.w + vbf.w), ig = sigmoidf_(pi.w + vbi.w);
        float og = sigmoidf_(po.w + vbo.w), cg = tanhf(pc.w + vbc.w);
        cn.w = ig * cg + fg * vc.w; hn.w = og * tanhf(cn.w);
    }
    *(float4*)&out[hb] = hn;
    *(float4*)&out[(size_t)NN * HH + hb] = cn;
}

// ---------------- launch ----------------
extern "C" void kernel_launch(void* const* d_in, const int* in_sizes, int n_in,
                              void* d_out, int out_size, void* d_ws, size_t ws_size,
                              hipStream_t stream) {
    const float* x   = (const float*)d_in[0];
    const float* h   = (const float*)d_in[1];
    const float* c   = (const float*)d_in[2];
    const float* lap = (const float*)d_in[3];
    const int*   pos = (const int*)d_in[4];
    const float* Wfh = (const float*)d_in[5];
    const float* Wfx = (const float*)d_in[6];
    const float* bf  = (const float*)d_in[7];
    const float* Wih = (const float*)d_in[8];
    const float* Wix = (const float*)d_in[9];
    const float* bi  = (const float*)d_in[10];
    const float* Woh = (const float*)d_in[11];
    const float* Wox = (const float*)d_in[12];
    const float* bo  = (const float*)d_in[13];
    const float* Wch = (const float*)d_in[14];
    const float* Wcx = (const float*)d_in[15];
    const float* bc  = (const float*)d_in[16];
    float* out = (float*)d_out;

    uint8_t* ws = (uint8_t*)d_ws;
    size_t off = 0;
    auto take = [&](size_t bytes) -> void* {
        void* p = ws + off;
        off += (bytes + 255) & ~(size_t)255;
        return p;
    };
    int*      flag = (int*)take(4);
    uint32_t* rcnt = (uint32_t*)take((size_t)NN * 4);
    uint2*    cpack= (uint2*)take((size_t)NN * RCAP * 8);                 //  8.4 MB
    uint32_t* cpk  = (uint32_t*)take((size_t)NN * RCAP * 4);              //  4.2 MB
    unsigned short* Amat = (unsigned short*)take((size_t)NN * KW * 2);    // 25.2 MB
    __hip_bfloat16* Bmat = (__hip_bfloat16*)take((size_t)MW * KW * 2);    //  3.1 MB
    float*    Cpre = (float*)take((size_t)NN * MW * 4);                   // 33.5 MB

    init_small<<<NN / 256, 256, 0, stream>>>(rcnt, pos, flag);
    scatter_fixed<<<EE / 256, 256, 0, stream>>>(pos, flag, lap, rcnt, cpack);
    dedup_rows<<<NN / 4, 256, 0, stream>>>(rcnt, cpack, cpk);

    pack_T0<<<3072, 256, 0, stream>>>(h, x, Amat);
    pack_B<<<(MW * KW + 255) / 256, 256, 0, stream>>>(Wfh, Wih, Woh, Wch,
                                                      Wfx, Wix, Wox, Wcx, Bmat);

    int sg = 1024 + 512;
    // col bases: h levels at 0,256,512,768 ; x levels at 1024,1152,1280,1408
    // level 1: T1 = L@T0
    spmv_cheb_dual<<<sg, 256, 0, stream>>>(rcnt, cpk, Amat,
        0, 0, 256, 1024, 1024, 1152, 1.0f, 0.0f);
    // level 2: T2 = 2 L@T1 - T0
    spmv_cheb_dual<<<sg, 256, 0, stream>>>(rcnt, cpk, Amat,
        256, 0, 512, 1152, 1024, 1280, 2.0f, -1.0f);
    // level 3: T3 = 2 L@T2 - T1
    spmv_cheb_dual<<<sg, 256, 0, stream>>>(rcnt, cpk, Amat,
        512, 256, 768, 1280, 1152, 1408, 2.0f, -1.0f);

    gemm_mfma<<<512, 256, 0, stream>>>((const __hip_bfloat16*)Amat, Bmat, Cpre);

    lstm_ew<<<(NN * HH / 4 + 255) / 256, 256, 0, stream>>>(Cpre, bf, bi, bo, bc, c, out);
}

// Round 16
// 155.102 us; speedup vs baseline: 1.2452x; 1.2452x over previous
//
#include <hip/hip_runtime.h>
#include <hip/hip_bf16.h>
#include <cstdint>

// Problem constants (fixed by reference)
#define NN 8192
#define HH 256
#define II 128
#define KORD 4
#define EE 262144
#define KW 1536          // GEMM K = 4*(256+128)
#define MW 1024          // GEMM output cols = 4 gates * 256
#define RCAP 128         // fixed row capacity (Poisson(32): P(>128) ~ 1e-40)
#define BK 64            // GEMM K-step (full 128B L2 lines per row)

typedef __attribute__((ext_vector_type(8))) short bf16x8;
typedef __attribute__((ext_vector_type(8))) unsigned short u16x8;
typedef __attribute__((ext_vector_type(4))) float f32x4;

__device__ __forceinline__ float bf2f(unsigned short u) {
    union { uint32_t i; float f; } x; x.i = ((uint32_t)u) << 16; return x.f;
}
__device__ __forceinline__ unsigned short f2bf(float f) {
    __hip_bfloat16 b = __float2bfloat16(f);
    return *(unsigned short*)&b;
}

// ---------------- pos layout handling (int32 vs int64 words) ----------------
__device__ __forceinline__ void read_pos(const int* __restrict__ pos, int flag,
                                         int e, int& r, int& c) {
    if (flag) { r = pos[4 * e]; c = pos[4 * e + 2]; }   // int64 little-endian
    else      { r = pos[2 * e]; c = pos[2 * e + 1]; }   // int32
}

// ---------------- fused prep: init + pack_T0 + pack_B (one launch) ---------
// sections: [0,32) init rcnt+flag | [32,3104) pack_T0 | [3104,9248) pack_B
__global__ void prep_all(const float* __restrict__ h, const float* __restrict__ x,
                         unsigned short* __restrict__ Hb, unsigned short* __restrict__ Xb,
                         unsigned short* __restrict__ Am,
                         const float* __restrict__ Wfh, const float* __restrict__ Wih,
                         const float* __restrict__ Woh, const float* __restrict__ Wch,
                         const float* __restrict__ Wfx, const float* __restrict__ Wix,
                         const float* __restrict__ Wox, const float* __restrict__ Wcx,
                         __hip_bfloat16* __restrict__ Bm,
                         const int* __restrict__ pos,
                         uint32_t* __restrict__ rcnt, int* __restrict__ flag) {
    int bid = blockIdx.x;
    if (bid < 32) {
        int i = bid * 256 + threadIdx.x;
        if (i < NN) rcnt[i] = 0u;
        if (i == 0) {
            int f = 1;
            for (int k = 0; k < 128; ++k) {
                if (pos[2 * k + 1] != 0) { f = 0; break; }
            }
            *flag = f;
        }
        return;
    }
    if (bid < 3104) {
        int idx = (bid - 32) * 256 + threadIdx.x;   // over NN*96 (4-elem units)
        int n, q, col;
        const float* src;
        unsigned short* st;
        if (idx < NN * 64) { n = idx >> 6; q = (idx & 63) * 4; src = &h[(size_t)n * HH + q]; st = &Hb[(size_t)n * HH + q]; col = q; }
        else { int ix = idx - NN * 64; n = ix >> 5; q = (ix & 31) * 4; src = &x[(size_t)n * II + q]; st = &Xb[(size_t)n * II + q]; col = 1024 + q; }
        float4 v = *(const float4*)src;
        ushort4 pk;
        pk.x = f2bf(v.x); pk.y = f2bf(v.y); pk.z = f2bf(v.z); pk.w = f2bf(v.w);
        *(ushort4*)st = pk;
        *(ushort4*)&Am[(size_t)n * KW + col] = pk;
        return;
    }
    {
        int idx = (bid - 3104) * 256 + threadIdx.x;  // over MW*KW
        int m = idx / KW, j = idx - m * KW;
        int g = m >> 8, hh = m & 255;
        const float* Wh = (g == 0) ? Wfh : (g == 1) ? Wih : (g == 2) ? Woh : Wch;
        const float* Wx = (g == 0) ? Wfx : (g == 1) ? Wix : (g == 2) ? Wox : Wcx;
        float v;
        if (j < 1024) { int k = j >> 8, f = j & 255; v = Wh[((size_t)k * HH + hh) * HH + f]; }
        else { int jj = j - 1024; int k = jj >> 7, f = jj & 127; v = Wx[((size_t)k * HH + hh) * II + f]; }
        Bm[idx] = __float2bfloat16(v);
    }
}

// ---------------- scatter into fixed-stride rows ---------------------------
// meta = (e+1)<<13 | c  (c: 13 bits, e+1: 19 bits) ; value kept raw f32
__global__ void scatter_fixed(const int* __restrict__ pos, const int* __restrict__ flagp,
                              const float* __restrict__ lap,
                              uint32_t* __restrict__ rcnt, uint2* __restrict__ cpack) {
    int e = blockIdx.x * blockDim.x + threadIdx.x;
    if (e >= EE) return;
    int flag = *flagp;
    int r, c; read_pos(pos, flag, e, r, c);
    uint32_t slot = atomicAdd(&rcnt[r], 1u);
    if (slot < RCAP) {
        uint2 p;
        p.x = ((uint32_t)(e + 1) << 13) | (uint32_t)c;
        p.y = __float_as_uint(lap[e]);
        cpack[(size_t)r * RCAP + slot] = p;
    }
}

// ---------------- in-row dedup: last-write (max e) wins --------------------
// wave per row; pairwise compare via shfl broadcast; strips meta -> plain c
__global__ __launch_bounds__(256) void dedup_rows(uint32_t* __restrict__ rcnt,
                                                  uint2* __restrict__ cpack) {
    int r = blockIdx.x * 4 + (threadIdx.x >> 6);
    int lane = threadIdx.x & 63;
    uint32_t lenu = rcnt[r];
    int len = (lenu > RCAP) ? RCAP : (int)lenu;
    uint2* base = &cpack[(size_t)r * RCAP];
    uint32_t m0 = 0u, m1 = 0u;
    if (lane < len) m0 = base[lane].x;
    if (64 + lane < len) m1 = base[64 + lane].x;
    bool lose0 = false, lose1 = false;
    int nchunk = (len + 63) >> 6;
    for (int ch = 0; ch < nchunk; ++ch) {
        int cl = len - ch * 64; if (cl > 64) cl = 64;
        for (int i = 0; i < cl; ++i) {
            uint32_t mi = __shfl(ch == 0 ? m0 : m1, i);
            lose0 |= (((mi ^ m0) & 8191u) == 0u) && (mi > m0);
            lose1 |= (((mi ^ m1) & 8191u) == 0u) && (mi > m1);
        }
    }
    if (lane < len) {
        base[lane].x = m0 & 8191u;
        if (lose0) base[lane].y = 0u;
    }
    if (64 + lane < len) {
        base[64 + lane].x = m1 & 8191u;
        if (lose1) base[64 + lane].y = 0u;
    }
    if (lane == 0 && lenu > RCAP) rcnt[r] = RCAP;
}

// ---------------- SpMV on bf16 state: f32 accum, cached 16B gathers, unroll 4
template <int F, bool LAST>
__device__ __forceinline__ void spmv_seg(
    const uint32_t* __restrict__ rcnt, const uint2* __restrict__ cp,
    const unsigned short* __restrict__ Xb, const unsigned short* __restrict__ Pb,
    unsigned short* __restrict__ Yb, unsigned short* __restrict__ Am, int colbase,
    float a, float b, int r, int lane) {
    uint32_t len = rcnt[r]; if (len > RCAP) len = RCAP;
    uint32_t s = (uint32_t)r * RCAP, e = s + len;
    int off = lane * 8;
    float acc[8];
#pragma unroll
    for (int j = 0; j < 8; ++j) acc[j] = 0.0f;
    uint32_t i = s;
    for (; i + 4 <= e; i += 4) {
        uint2 p0 = cp[i], p1 = cp[i + 1], p2 = cp[i + 2], p3 = cp[i + 3];
        u16x8 g0 = *(const u16x8*)&Xb[(size_t)p0.x * F + off];
        u16x8 g1 = *(const u16x8*)&Xb[(size_t)p1.x * F + off];
        u16x8 g2 = *(const u16x8*)&Xb[(size_t)p2.x * F + off];
        u16x8 g3 = *(const u16x8*)&Xb[(size_t)p3.x * F + off];
        float v0 = __uint_as_float(p0.y), v1 = __uint_as_float(p1.y);
        float v2 = __uint_as_float(p2.y), v3 = __uint_as_float(p3.y);
#pragma unroll
        for (int j = 0; j < 8; ++j)
            acc[j] += v0 * bf2f(g0[j]) + v1 * bf2f(g1[j]) +
                      v2 * bf2f(g2[j]) + v3 * bf2f(g3[j]);
    }
    for (; i < e; ++i) {
        uint2 p0 = cp[i];
        u16x8 g0 = *(const u16x8*)&Xb[(size_t)p0.x * F + off];
        float v0 = __uint_as_float(p0.y);
#pragma unroll
        for (int j = 0; j < 8; ++j) acc[j] += v0 * bf2f(g0[j]);
    }
    u16x8 ob;
    if (b != 0.0f) {
        u16x8 pv = *(const u16x8*)&Pb[(size_t)r * F + off];
#pragma unroll
        for (int j = 0; j < 8; ++j) ob[j] = f2bf(a * acc[j] + b * bf2f(pv[j]));
    } else {
#pragma unroll
        for (int j = 0; j < 8; ++j) ob[j] = f2bf(a * acc[j]);
    }
    if (!LAST) *(u16x8*)&Yb[(size_t)r * F + off] = ob;
    *(u16x8*)&Am[(size_t)r * KW + colbase + off] = ob;
}

// one launch = one Chebyshev level for BOTH h (F=256) and x (F=128)
#define NBH (NN / 8)    // h: 32 lanes/row, 8 rows/block
#define NBX (NN / 16)   // x: 16 lanes/row, 16 rows/block
template <bool LAST>
__global__ __launch_bounds__(256) void spmv_cheb_dual(
    const uint32_t* __restrict__ rcnt, const uint2* __restrict__ cp,
    const unsigned short* __restrict__ Xh, const unsigned short* __restrict__ Ph,
    unsigned short* __restrict__ Yh, int cbh,
    const unsigned short* __restrict__ Xx, const unsigned short* __restrict__ Px,
    unsigned short* __restrict__ Yx, int cbx,
    unsigned short* __restrict__ Am, float a, float b) {
    int bid = blockIdx.x, t = threadIdx.x;
    if (bid < NBH) {
        int r = bid * 8 + (t >> 5), lane = t & 31;
        spmv_seg<HH, LAST>(rcnt, cp, Xh, Ph, Yh, Am, cbh, a, b, r, lane);
    } else {
        int r = (bid - NBH) * 16 + (t >> 4), lane = t & 15;
        spmv_seg<II, LAST>(rcnt, cp, Xx, Px, Yx, Am, cbx, a, b, r, lane);
    }
}

// ---------------- bf16 MFMA GEMM: BK=64, dbuf 2-phase, slot-8 LDS swizzle ---
// LDS tile [128 rows][8 slots of 16B] (row = 128B = full L2 line staged).
// Swizzle: global slot g stored at LDS slot g^(row&7); reader XORs same term.
__device__ __forceinline__ void gload_lds16(const void* g, void* l) {
    __builtin_amdgcn_global_load_lds(
        (const __attribute__((address_space(1))) void*)g,
        (__attribute__((address_space(3))) void*)l, 16, 0, 0);
}

__device__ __forceinline__ void stage_side(const __hip_bfloat16* __restrict__ G,
                                           int r0, int kk, int t, short* lds) {
#pragma unroll
    for (int s = 0; s < 4; ++s) {
        int e = (s * 256 + t) * 8;        // elem in [128][64] tile
        int row = e >> 6;
        int kks = ((((e >> 3) & 7) ^ (row & 7)) << 3);  // pre-swizzled source
        gload_lds16(&G[(size_t)(r0 + row) * KW + kk + kks], &lds[e]);
    }
}

__global__ __launch_bounds__(256) void gemm_mfma(
    const __hip_bfloat16* __restrict__ A,   // [NN][KW]
    const __hip_bfloat16* __restrict__ B,   // [MW][KW]
    float* __restrict__ C) {                // [NN][MW]
    __shared__ short Alds[2][128 * BK];
    __shared__ short Blds[2][128 * BK];
    int bid = blockIdx.x;
    int sw = (bid & 7) * 64 + (bid >> 3);
    int m0 = (sw & 7) * 128;    // col tile
    int n0 = (sw >> 3) * 128;   // row tile
    int t = threadIdx.x;
    int w = t >> 6, l = t & 63;
    int wr = w >> 1, wc = w & 1;
    int lrow = l & 15, q = l >> 4;

    f32x4 acc[4][4];
#pragma unroll
    for (int i = 0; i < 4; ++i)
#pragma unroll
        for (int j = 0; j < 4; ++j) acc[i][j] = (f32x4)0.0f;

    stage_side(A, n0, 0, t, Alds[0]);
    stage_side(B, m0, 0, t, Blds[0]);
    __syncthreads();

    int cur = 0;
    for (int k0 = 0; k0 < KW; k0 += BK) {
        if (k0 + BK < KW) {
            stage_side(A, n0, k0 + BK, t, Alds[cur ^ 1]);
            stage_side(B, m0, k0 + BK, t, Blds[cur ^ 1]);
        }
#pragma unroll
        for (int h = 0; h < 2; ++h) {
            int sl = (((h << 2) | q) ^ (lrow & 7)) << 3;  // swizzled ds_read slot
            bf16x8 af[4], bfr[4];
#pragma unroll
            for (int i = 0; i < 4; ++i)
                af[i] = *(const bf16x8*)&Alds[cur][(wr * 64 + i * 16 + lrow) * BK + sl];
#pragma unroll
            for (int j = 0; j < 4; ++j)
                bfr[j] = *(const bf16x8*)&Blds[cur][(wc * 64 + j * 16 + lrow) * BK + sl];
#pragma unroll
            for (int i = 0; i < 4; ++i)
#pragma unroll
                for (int j = 0; j < 4; ++j)
                    acc[i][j] = __builtin_amdgcn_mfma_f32_16x16x32_bf16(af[i], bfr[j], acc[i][j], 0, 0, 0);
        }
        __syncthreads();
        cur ^= 1;
    }

    int r4 = (l >> 4) * 4;
#pragma unroll
    for (int i = 0; i < 4; ++i)
#pragma unroll
        for (int j = 0; j < 4; ++j)
#pragma unroll
            for (int r = 0; r < 4; ++r) {
                int row = n0 + wr * 64 + i * 16 + r4 + r;
                int col = m0 + wc * 64 + j * 16 + lrow;
                C[(size_t)row * MW + col] = acc[i][j][r];
            }
}

// ---------------- LSTM elementwise epilogue ----------------
__device__ __forceinline__ float sigmoidf_(float x) { return 1.0f / (1.0f + expf(-x)); }

__global__ __launch_bounds__(256) void lstm_ew(
    const float* __restrict__ C,            // [NN][MW] preacts, gate g at col g*256+h
    const float* __restrict__ bf, const float* __restrict__ bi,
    const float* __restrict__ bo, const float* __restrict__ bc,
    const float* __restrict__ cin, float* __restrict__ out) {
    int i = blockIdx.x * blockDim.x + threadIdx.x;  // over NN*HH/4
    if (i >= NN * HH / 4) return;
    int n = i >> 6;           // HH/4 = 64 float4 per row
    int h4 = (i & 63) * 4;
    size_t cb = (size_t)n * MW;
    size_t hb = (size_t)n * HH + h4;
    float4 pf = *(const float4*)&C[cb + 0 * HH + h4];
    float4 pi = *(const float4*)&C[cb + 1 * HH + h4];
    float4 po = *(const float4*)&C[cb + 2 * HH + h4];
    float4 pc = *(const float4*)&C[cb + 3 * HH + h4];
    float4 vbf = *(const float4*)&bf[hb];
    float4 vbi = *(const float4*)&bi[hb];
    float4 vbo = *(const float4*)&bo[hb];
    float4 vbc = *(const float4*)&bc[hb];
    float4 vc  = *(const float4*)&cin[hb];
    float4 hn, cn;
    {
        float fg = sigmoidf_(pf.x + vbf.x), ig = sigmoidf_(pi.x + vbi.x);
        float og = sigmoidf_(po.x + vbo.x), cg = tanhf(pc.x + vbc.x);
        cn.x = ig * cg + fg * vc.x; hn.x = og * tanhf(cn.x);
    }
    {
        float fg = sigmoidf_(pf.y + vbf.y), ig = sigmoidf_(pi.y + vbi.y);
        float og = sigmoidf_(po.y + vbo.y), cg = tanhf(pc.y + vbc.y);
        cn.y = ig * cg + fg * vc.y; hn.y = og * tanhf(cn.y);
    }
    {
        float fg = sigmoidf_(pf.z + vbf.z), ig = sigmoidf_(pi.z + vbi.z);
        float og = sigmoidf_(po.z + vbo.z), cg = tanhf(pc.z + vbc.z);
        cn.z = ig * cg + fg * vc.z; hn.z = og * tanhf(cn.z);
    }
    {
        float fg = sigmoidf_(pf.w + vbf.w), ig = sigmoidf_(pi.w + vbi.w);
        float og = sigmoidf_(po.w + vbo.w), cg = tanhf(pc.w + vbc.w);
        cn.w = ig * cg + fg * vc.w; hn.w = og * tanhf(cn.w);
    }
    *(float4*)&out[hb] = hn;
    *(float4*)&out[(size_t)NN * HH + hb] = cn;
}

// ---------------- launch ----------------
extern "C" void kernel_launch(void* const* d_in, const int* in_sizes, int n_in,
                              void* d_out, int out_size, void* d_ws, size_t ws_size,
                              hipStream_t stream) {
    const float* x   = (const float*)d_in[0];
    const float* h   = (const float*)d_in[1];
    const float* c   = (const float*)d_in[2];
    const float* lap = (const float*)d_in[3];
    const int*   pos = (const int*)d_in[4];
    const float* Wfh = (const float*)d_in[5];
    const float* Wfx = (const float*)d_in[6];
    const float* bf  = (const float*)d_in[7];
    const float* Wih = (const float*)d_in[8];
    const float* Wix = (const float*)d_in[9];
    const float* bi  = (const float*)d_in[10];
    const float* Woh = (const float*)d_in[11];
    const float* Wox = (const float*)d_in[12];
    const float* bo  = (const float*)d_in[13];
    const float* Wch = (const float*)d_in[14];
    const float* Wcx = (const float*)d_in[15];
    const float* bc  = (const float*)d_in[16];
    float* out = (float*)d_out;

    uint8_t* ws = (uint8_t*)d_ws;
    size_t off = 0;
    auto take = [&](size_t bytes) -> void* {
        void* p = ws + off;
        off += (bytes + 255) & ~(size_t)255;
        return p;
    };
    int*      flag = (int*)take(4);
    uint32_t* rcnt = (uint32_t*)take((size_t)NN * 4);
    uint2*    cpack= (uint2*)take((size_t)NN * RCAP * 8);                 //  8.4 MB
    unsigned short* Hb = (unsigned short*)take((size_t)3 * NN * HH * 2);  // levels 0..2
    unsigned short* Xb = (unsigned short*)take((size_t)3 * NN * II * 2);
    unsigned short* Amat = (unsigned short*)take((size_t)NN * KW * 2);    // 25.2 MB
    __hip_bfloat16* Bmat = (__hip_bfloat16*)take((size_t)MW * KW * 2);    //  3.1 MB
    float*    Cpre = (float*)take((size_t)NN * MW * 4);                   // 33.5 MB

    // fused prep: rcnt/flag init + T0 pack + B pack, one launch
    prep_all<<<9248, 256, 0, stream>>>(h, x, Hb, Xb, Amat,
                                       Wfh, Wih, Woh, Wch, Wfx, Wix, Wox, Wcx,
                                       Bmat, pos, rcnt, flag);
    scatter_fixed<<<EE / 256, 256, 0, stream>>>(pos, flag, lap, rcnt, cpack);
    dedup_rows<<<NN / 4, 256, 0, stream>>>(rcnt, cpack);

    unsigned short* Hb0 = Hb;
    unsigned short* Hb1 = Hb + (size_t)NN * HH;
    unsigned short* Hb2 = Hb1 + (size_t)NN * HH;
    unsigned short* Xb0 = Xb;
    unsigned short* Xb1 = Xb + (size_t)NN * II;
    unsigned short* Xb2 = Xb1 + (size_t)NN * II;

    int sg = NBH + NBX;   // 1024 + 512 blocks
    // level 1: T1 = L@T0
    spmv_cheb_dual<false><<<sg, 256, 0, stream>>>(rcnt, cpack,
        Hb0, Hb0, Hb1, 256, Xb0, Xb0, Xb1, 1152, Amat, 1.0f, 0.0f);
    // level 2: T2 = 2 L@T1 - T0
    spmv_cheb_dual<false><<<sg, 256, 0, stream>>>(rcnt, cpack,
        Hb1, Hb0, Hb2, 512, Xb1, Xb0, Xb2, 1280, Amat, 2.0f, -1.0f);
    // level 3: T3 = 2 L@T2 - T1 (A-matrix only)
    spmv_cheb_dual<true><<<sg, 256, 0, stream>>>(rcnt, cpack,
        Hb2, Hb1, nullptr, 768, Xb2, Xb1, nullptr, 1408, Amat, 2.0f, -1.0f);

    gemm_mfma<<<512, 256, 0, stream>>>((const __hip_bfloat16*)Amat, Bmat, Cpre);

    lstm_ew<<<(NN * HH / 4 + 255) / 256, 256, 0, stream>>>(Cpre, bf, bi, bo, bc, c, out);
}

// Round 17
// 152.746 us; speedup vs baseline: 1.2644x; 1.0154x over previous
//
#include <hip/hip_runtime.h>
#include <hip/hip_bf16.h>
#include <cstdint>

// Problem constants (fixed by reference)
#define NN 8192
#define HH 256
#define II 128
#define KORD 4
#define EE 262144
#define KW 1536          // GEMM K = 4*(256+128)
#define MW 1024          // GEMM output cols = 4 gates * 256
#define RCAP 128         // fixed row capacity (Poisson(32): P(>128) ~ 1e-40)
#define BK 64            // GEMM K-step (full 128B L2 lines per row)

typedef __attribute__((ext_vector_type(8))) short bf16x8;
typedef __attribute__((ext_vector_type(8))) unsigned short u16x8;
typedef __attribute__((ext_vector_type(4))) float f32x4;

__device__ __forceinline__ float bf2f(unsigned short u) {
    union { uint32_t i; float f; } x; x.i = ((uint32_t)u) << 16; return x.f;
}
__device__ __forceinline__ unsigned short f2bf(float f) {
    __hip_bfloat16 b = __float2bfloat16(f);
    return *(unsigned short*)&b;
}

// ---------------- pos layout handling (int32 vs int64 words) ----------------
__device__ __forceinline__ void read_pos(const int* __restrict__ pos, int flag,
                                         int e, int& r, int& c) {
    if (flag) { r = pos[4 * e]; c = pos[4 * e + 2]; }   // int64 little-endian
    else      { r = pos[2 * e]; c = pos[2 * e + 1]; }   // int32
}

// ---------------- fused prep: init + pack_T0 + pack_B (one launch) ---------
// sections: [0,32) init rcnt+flag | [32,3104) pack_T0 | [3104,9248) pack_B
__global__ void prep_all(const float* __restrict__ h, const float* __restrict__ x,
                         unsigned short* __restrict__ Hb, unsigned short* __restrict__ Xb,
                         unsigned short* __restrict__ Am,
                         const float* __restrict__ Wfh, const float* __restrict__ Wih,
                         const float* __restrict__ Woh, const float* __restrict__ Wch,
                         const float* __restrict__ Wfx, const float* __restrict__ Wix,
                         const float* __restrict__ Wox, const float* __restrict__ Wcx,
                         __hip_bfloat16* __restrict__ Bm,
                         const int* __restrict__ pos,
                         uint32_t* __restrict__ rcnt, int* __restrict__ flag) {
    int bid = blockIdx.x;
    if (bid < 32) {
        int i = bid * 256 + threadIdx.x;
        if (i < NN) rcnt[i] = 0u;
        if (i == 0) {
            int f = 1;
            for (int k = 0; k < 128; ++k) {
                if (pos[2 * k + 1] != 0) { f = 0; break; }
            }
            *flag = f;
        }
        return;
    }
    if (bid < 3104) {
        int idx = (bid - 32) * 256 + threadIdx.x;   // over NN*96 (4-elem units)
        int n, q, col;
        const float* src;
        unsigned short* st;
        if (idx < NN * 64) { n = idx >> 6; q = (idx & 63) * 4; src = &h[(size_t)n * HH + q]; st = &Hb[(size_t)n * HH + q]; col = q; }
        else { int ix = idx - NN * 64; n = ix >> 5; q = (ix & 31) * 4; src = &x[(size_t)n * II + q]; st = &Xb[(size_t)n * II + q]; col = 1024 + q; }
        float4 v = *(const float4*)src;
        ushort4 pk;
        pk.x = f2bf(v.x); pk.y = f2bf(v.y); pk.z = f2bf(v.z); pk.w = f2bf(v.w);
        *(ushort4*)st = pk;
        *(ushort4*)&Am[(size_t)n * KW + col] = pk;
        return;
    }
    {
        int idx = (bid - 3104) * 256 + threadIdx.x;  // over MW*KW
        int m = idx / KW, j = idx - m * KW;
        int g = m >> 8, hh = m & 255;
        const float* Wh = (g == 0) ? Wfh : (g == 1) ? Wih : (g == 2) ? Woh : Wch;
        const float* Wx = (g == 0) ? Wfx : (g == 1) ? Wix : (g == 2) ? Wox : Wcx;
        float v;
        if (j < 1024) { int k = j >> 8, f = j & 255; v = Wh[((size_t)k * HH + hh) * HH + f]; }
        else { int jj = j - 1024; int k = jj >> 7, f = jj & 127; v = Wx[((size_t)k * HH + hh) * II + f]; }
        Bm[idx] = __float2bfloat16(v);
    }
}

// ---------------- scatter into fixed-stride rows ---------------------------
// meta = (e+1)<<13 | c  (c: 13 bits, e+1: 19 bits) ; value kept raw f32
__global__ void scatter_fixed(const int* __restrict__ pos, const int* __restrict__ flagp,
                              const float* __restrict__ lap,
                              uint32_t* __restrict__ rcnt, uint2* __restrict__ cpack) {
    int e = blockIdx.x * blockDim.x + threadIdx.x;
    if (e >= EE) return;
    int flag = *flagp;
    int r, c; read_pos(pos, flag, e, r, c);
    uint32_t slot = atomicAdd(&rcnt[r], 1u);
    if (slot < RCAP) {
        uint2 p;
        p.x = ((uint32_t)(e + 1) << 13) | (uint32_t)c;
        p.y = __float_as_uint(lap[e]);
        cpack[(size_t)r * RCAP + slot] = p;
    }
}

// ---------------- in-row dedup: last-write (max e) wins --------------------
// wave per row; pairwise compare via shfl broadcast; strips meta -> plain c
__global__ __launch_bounds__(256) void dedup_rows(uint32_t* __restrict__ rcnt,
                                                  uint2* __restrict__ cpack) {
    int r = blockIdx.x * 4 + (threadIdx.x >> 6);
    int lane = threadIdx.x & 63;
    uint32_t lenu = rcnt[r];
    int len = (lenu > RCAP) ? RCAP : (int)lenu;
    uint2* base = &cpack[(size_t)r * RCAP];
    uint32_t m0 = 0u, m1 = 0u;
    if (lane < len) m0 = base[lane].x;
    if (64 + lane < len) m1 = base[64 + lane].x;
    bool lose0 = false, lose1 = false;
    int nchunk = (len + 63) >> 6;
    for (int ch = 0; ch < nchunk; ++ch) {
        int cl = len - ch * 64; if (cl > 64) cl = 64;
        for (int i = 0; i < cl; ++i) {
            uint32_t mi = __shfl(ch == 0 ? m0 : m1, i);
            lose0 |= (((mi ^ m0) & 8191u) == 0u) && (mi > m0);
            lose1 |= (((mi ^ m1) & 8191u) == 0u) && (mi > m1);
        }
    }
    if (lane < len) {
        base[lane].x = m0 & 8191u;
        if (lose0) base[lane].y = 0u;
    }
    if (64 + lane < len) {
        base[64 + lane].x = m1 & 8191u;
        if (lose1) base[64 + lane].y = 0u;
    }
    if (lane == 0 && lenu > RCAP) rcnt[r] = RCAP;
}

// ---------------- SpMV on bf16 state: f32 accum, cached 16B gathers, unroll 4
template <int F, bool LAST>
__device__ __forceinline__ void spmv_seg(
    const uint32_t* __restrict__ rcnt, const uint2* __restrict__ cp,
    const unsigned short* __restrict__ Xb, const unsigned short* __restrict__ Pb,
    unsigned short* __restrict__ Yb, unsigned short* __restrict__ Am, int colbase,
    float a, float b, int r, int lane) {
    uint32_t len = rcnt[r]; if (len > RCAP) len = RCAP;
    uint32_t s = (uint32_t)r * RCAP, e = s + len;
    int off = lane * 8;
    float acc[8];
#pragma unroll
    for (int j = 0; j < 8; ++j) acc[j] = 0.0f;
    uint32_t i = s;
    for (; i + 4 <= e; i += 4) {
        uint2 p0 = cp[i], p1 = cp[i + 1], p2 = cp[i + 2], p3 = cp[i + 3];
        u16x8 g0 = *(const u16x8*)&Xb[(size_t)p0.x * F + off];
        u16x8 g1 = *(const u16x8*)&Xb[(size_t)p1.x * F + off];
        u16x8 g2 = *(const u16x8*)&Xb[(size_t)p2.x * F + off];
        u16x8 g3 = *(const u16x8*)&Xb[(size_t)p3.x * F + off];
        float v0 = __uint_as_float(p0.y), v1 = __uint_as_float(p1.y);
        float v2 = __uint_as_float(p2.y), v3 = __uint_as_float(p3.y);
#pragma unroll
        for (int j = 0; j < 8; ++j)
            acc[j] += v0 * bf2f(g0[j]) + v1 * bf2f(g1[j]) +
                      v2 * bf2f(g2[j]) + v3 * bf2f(g3[j]);
    }
    for (; i < e; ++i) {
        uint2 p0 = cp[i];
        u16x8 g0 = *(const u16x8*)&Xb[(size_t)p0.x * F + off];
        float v0 = __uint_as_float(p0.y);
#pragma unroll
        for (int j = 0; j < 8; ++j) acc[j] += v0 * bf2f(g0[j]);
    }
    u16x8 ob;
    if (b != 0.0f) {
        u16x8 pv = *(const u16x8*)&Pb[(size_t)r * F + off];
#pragma unroll
        for (int j = 0; j < 8; ++j) ob[j] = f2bf(a * acc[j] + b * bf2f(pv[j]));
    } else {
#pragma unroll
        for (int j = 0; j < 8; ++j) ob[j] = f2bf(a * acc[j]);
    }
    if (!LAST) *(u16x8*)&Yb[(size_t)r * F + off] = ob;
    *(u16x8*)&Am[(size_t)r * KW + colbase + off] = ob;
}

// one launch = one Chebyshev level for BOTH h (F=256) and x (F=128)
#define NBH (NN / 8)    // h: 32 lanes/row, 8 rows/block
#define NBX (NN / 16)   // x: 16 lanes/row, 16 rows/block
template <bool LAST>
__global__ __launch_bounds__(256) void spmv_cheb_dual(
    const uint32_t* __restrict__ rcnt, const uint2* __restrict__ cp,
    const unsigned short* __restrict__ Xh, const unsigned short* __restrict__ Ph,
    unsigned short* __restrict__ Yh, int cbh,
    const unsigned short* __restrict__ Xx, const unsigned short* __restrict__ Px,
    unsigned short* __restrict__ Yx, int cbx,
    unsigned short* __restrict__ Am, float a, float b) {
    int bid = blockIdx.x, t = threadIdx.x;
    if (bid < NBH) {
        int r = bid * 8 + (t >> 5), lane = t & 31;
        spmv_seg<HH, LAST>(rcnt, cp, Xh, Ph, Yh, Am, cbh, a, b, r, lane);
    } else {
        int r = (bid - NBH) * 16 + (t >> 4), lane = t & 15;
        spmv_seg<II, LAST>(rcnt, cp, Xx, Px, Yx, Am, cbx, a, b, r, lane);
    }
}

// ---------------- bf16 MFMA GEMM: BK=64, dbuf 2-phase, slot-8 LDS swizzle ---
// C output stored as bf16 (halves preact round-trip traffic).
__device__ __forceinline__ void gload_lds16(const void* g, void* l) {
    __builtin_amdgcn_global_load_lds(
        (const __attribute__((address_space(1))) void*)g,
        (__attribute__((address_space(3))) void*)l, 16, 0, 0);
}

__device__ __forceinline__ void stage_side(const __hip_bfloat16* __restrict__ G,
                                           int r0, int kk, int t, short* lds) {
#pragma unroll
    for (int s = 0; s < 4; ++s) {
        int e = (s * 256 + t) * 8;        // elem in [128][64] tile
        int row = e >> 6;
        int kks = ((((e >> 3) & 7) ^ (row & 7)) << 3);  // pre-swizzled source
        gload_lds16(&G[(size_t)(r0 + row) * KW + kk + kks], &lds[e]);
    }
}

__global__ __launch_bounds__(256) void gemm_mfma(
    const __hip_bfloat16* __restrict__ A,   // [NN][KW]
    const __hip_bfloat16* __restrict__ B,   // [MW][KW]
    unsigned short* __restrict__ C) {       // [NN][MW] bf16 preacts
    __shared__ short Alds[2][128 * BK];
    __shared__ short Blds[2][128 * BK];
    int bid = blockIdx.x;
    int sw = (bid & 7) * 64 + (bid >> 3);
    int m0 = (sw & 7) * 128;    // col tile
    int n0 = (sw >> 3) * 128;   // row tile
    int t = threadIdx.x;
    int w = t >> 6, l = t & 63;
    int wr = w >> 1, wc = w & 1;
    int lrow = l & 15, q = l >> 4;

    f32x4 acc[4][4];
#pragma unroll
    for (int i = 0; i < 4; ++i)
#pragma unroll
        for (int j = 0; j < 4; ++j) acc[i][j] = (f32x4)0.0f;

    stage_side(A, n0, 0, t, Alds[0]);
    stage_side(B, m0, 0, t, Blds[0]);
    __syncthreads();

    int cur = 0;
    for (int k0 = 0; k0 < KW; k0 += BK) {
        if (k0 + BK < KW) {
            stage_side(A, n0, k0 + BK, t, Alds[cur ^ 1]);
            stage_side(B, m0, k0 + BK, t, Blds[cur ^ 1]);
        }
#pragma unroll
        for (int h = 0; h < 2; ++h) {
            int sl = (((h << 2) | q) ^ (lrow & 7)) << 3;  // swizzled ds_read slot
            bf16x8 af[4], bfr[4];
#pragma unroll
            for (int i = 0; i < 4; ++i)
                af[i] = *(const bf16x8*)&Alds[cur][(wr * 64 + i * 16 + lrow) * BK + sl];
#pragma unroll
            for (int j = 0; j < 4; ++j)
                bfr[j] = *(const bf16x8*)&Blds[cur][(wc * 64 + j * 16 + lrow) * BK + sl];
#pragma unroll
            for (int i = 0; i < 4; ++i)
#pragma unroll
                for (int j = 0; j < 4; ++j)
                    acc[i][j] = __builtin_amdgcn_mfma_f32_16x16x32_bf16(af[i], bfr[j], acc[i][j], 0, 0, 0);
        }
        __syncthreads();
        cur ^= 1;
    }

    int r4 = (l >> 4) * 4;
#pragma unroll
    for (int i = 0; i < 4; ++i)
#pragma unroll
        for (int j = 0; j < 4; ++j)
#pragma unroll
            for (int r = 0; r < 4; ++r) {
                int row = n0 + wr * 64 + i * 16 + r4 + r;
                int col = m0 + wc * 64 + j * 16 + lrow;
                C[(size_t)row * MW + col] = f2bf(acc[i][j][r]);
            }
}

// ---------------- LSTM elementwise epilogue (bf16 preacts) ----------------
__device__ __forceinline__ float sigmoidf_(float x) { return 1.0f / (1.0f + expf(-x)); }

__global__ __launch_bounds__(256) void lstm_ew(
    const unsigned short* __restrict__ C,   // [NN][MW] bf16 preacts
    const float* __restrict__ bf, const float* __restrict__ bi,
    const float* __restrict__ bo, const float* __restrict__ bc,
    const float* __restrict__ cin, float* __restrict__ out) {
    int i = blockIdx.x * blockDim.x + threadIdx.x;  // over NN*HH/4
    if (i >= NN * HH / 4) return;
    int n = i >> 6;           // HH/4 = 64 quads per row
    int h4 = (i & 63) * 4;
    size_t cb = (size_t)n * MW;
    size_t hb = (size_t)n * HH + h4;
    ushort4 uf = *(const ushort4*)&C[cb + 0 * HH + h4];
    ushort4 ui = *(const ushort4*)&C[cb + 1 * HH + h4];
    ushort4 uo = *(const ushort4*)&C[cb + 2 * HH + h4];
    ushort4 uc = *(const ushort4*)&C[cb + 3 * HH + h4];
    float4 vbf = *(const float4*)&bf[hb];
    float4 vbi = *(const float4*)&bi[hb];
    float4 vbo = *(const float4*)&bo[hb];
    float4 vbc = *(const float4*)&bc[hb];
    float4 vc  = *(const float4*)&cin[hb];
    float4 hn, cn;
    {
        float fg = sigmoidf_(bf2f(uf.x) + vbf.x), ig = sigmoidf_(bf2f(ui.x) + vbi.x);
        float og = sigmoidf_(bf2f(uo.x) + vbo.x), cg = tanhf(bf2f(uc.x) + vbc.x);
        cn.x = ig * cg + fg * vc.x; hn.x = og * tanhf(cn.x);
    }
    {
        float fg = sigmoidf_(bf2f(uf.y) + vbf.y), ig = sigmoidf_(bf2f(ui.y) + vbi.y);
        float og = sigmoidf_(bf2f(uo.y) + vbo.y), cg = tanhf(bf2f(uc.y) + vbc.y);
        cn.y = ig * cg + fg * vc.y; hn.y = og * tanhf(cn.y);
    }
    {
        float fg = sigmoidf_(bf2f(uf.z) + vbf.z), ig = sigmoidf_(bf2f(ui.z) + vbi.z);
        float og = sigmoidf_(bf2f(uo.z) + vbo.z), cg = tanhf(bf2f(uc.z) + vbc.z);
        cn.z = ig * cg + fg * vc.z; hn.z = og * tanhf(cn.z);
    }
    {
        float fg = sigmoidf_(bf2f(uf.w) + vbf.w), ig = sigmoidf_(bf2f(ui.w) + vbi.w);
        float og = sigmoidf_(bf2f(uo.w) + vbo.w), cg = tanhf(bf2f(uc.w) + vbc.w);
        cn.w = ig * cg + fg * vc.w; hn.w = og * tanhf(cn.w);
    }
    *(float4*)&out[hb] = hn;
    *(float4*)&out[(size_t)NN * HH + hb] = cn;
}

// ---------------- launch ----------------
extern "C" void kernel_launch(void* const* d_in, const int* in_sizes, int n_in,
                              void* d_out, int out_size, void* d_ws, size_t ws_size,
                              hipStream_t stream) {
    const float* x   = (const float*)d_in[0];
    const float* h   = (const float*)d_in[1];
    const float* c   = (const float*)d_in[2];
    const float* lap = (const float*)d_in[3];
    const int*   pos = (const int*)d_in[4];
    const float* Wfh = (const float*)d_in[5];
    const float* Wfx = (const float*)d_in[6];
    const float* bf  = (const float*)d_in[7];
    const float* Wih = (const float*)d_in[8];
    const float* Wix = (const float*)d_in[9];
    const float* bi  = (const float*)d_in[10];
    const float* Woh = (const float*)d_in[11];
    const float* Wox = (const float*)d_in[12];
    const float* bo  = (const float*)d_in[13];
    const float* Wch = (const float*)d_in[14];
    const float* Wcx = (const float*)d_in[15];
    const float* bc  = (const float*)d_in[16];
    float* out = (float*)d_out;

    uint8_t* ws = (uint8_t*)d_ws;
    size_t off = 0;
    auto take = [&](size_t bytes) -> void* {
        void* p = ws + off;
        off += (bytes + 255) & ~(size_t)255;
        return p;
    };
    int*      flag = (int*)take(4);
    uint32_t* rcnt = (uint32_t*)take((size_t)NN * 4);
    uint2*    cpack= (uint2*)take((size_t)NN * RCAP * 8);                 //  8.4 MB
    unsigned short* Hb = (unsigned short*)take((size_t)3 * NN * HH * 2);  // levels 0..2
    unsigned short* Xb = (unsigned short*)take((size_t)3 * NN * II * 2);
    unsigned short* Amat = (unsigned short*)take((size_t)NN * KW * 2);    // 25.2 MB
    __hip_bfloat16* Bmat = (__hip_bfloat16*)take((size_t)MW * KW * 2);    //  3.1 MB
    unsigned short* Cpre = (unsigned short*)take((size_t)NN * MW * 2);    // 16.8 MB

    // fused prep: rcnt/flag init + T0 pack + B pack, one launch
    prep_all<<<9248, 256, 0, stream>>>(h, x, Hb, Xb, Amat,
                                       Wfh, Wih, Woh, Wch, Wfx, Wix, Wox, Wcx,
                                       Bmat, pos, rcnt, flag);
    scatter_fixed<<<EE / 256, 256, 0, stream>>>(pos, flag, lap, rcnt, cpack);
    dedup_rows<<<NN / 4, 256, 0, stream>>>(rcnt, cpack);

    unsigned short* Hb0 = Hb;
    unsigned short* Hb1 = Hb + (size_t)NN * HH;
    unsigned short* Hb2 = Hb1 + (size_t)NN * HH;
    unsigned short* Xb0 = Xb;
    unsigned short* Xb1 = Xb + (size_t)NN * II;
    unsigned short* Xb2 = Xb1 + (size_t)NN * II;

    int sg = NBH + NBX;   // 1024 + 512 blocks
    // level 1: T1 = L@T0
    spmv_cheb_dual<false><<<sg, 256, 0, stream>>>(rcnt, cpack,
        Hb0, Hb0, Hb1, 256, Xb0, Xb0, Xb1, 1152, Amat, 1.0f, 0.0f);
    // level 2: T2 = 2 L@T1 - T0
    spmv_cheb_dual<false><<<sg, 256, 0, stream>>>(rcnt, cpack,
        Hb1, Hb0, Hb2, 512, Xb1, Xb0, Xb2, 1280, Amat, 2.0f, -1.0f);
    // level 3: T3 = 2 L@T2 - T1 (A-matrix only)
    spmv_cheb_dual<true><<<sg, 256, 0, stream>>>(rcnt, cpack,
        Hb2, Hb1, nullptr, 768, Xb2, Xb1, nullptr, 1408, Amat, 2.0f, -1.0f);

    gemm_mfma<<<512, 256, 0, stream>>>((const __hip_bfloat16*)Amat, Bmat, Cpre);

    lstm_ew<<<(NN * HH / 4 + 255) / 256, 256, 0, stream>>>(Cpre, bf, bi, bo, bc, c, out);
}